// Round 11
// baseline (266.513 us; speedup 1.0000x reference)
//
#include <hip/hip_runtime.h>

// ---------------------------------------------------------------------------
// Discriminator fused pipeline for MI355X (gfx950).
// R11: layers 2/3 use K=128 block-scaled MFMA (mfma_scale_f32_16x16x128_f8f6f4,
// e4m3, unit scales -> numerically identical to R10's plain fp8) — 4x fewer
// MFMA instructions, ~2.3x matrix-pipe rate. LDS read pattern kept bit-for-bit
// from R10 (4 x b64 per 32-B fragment, chunk-XOR swizzle). A-weights in
// fragment-major layout: lane-contiguous 32 B, natural k order (2 x 16-B loads).
//
//   h1[b, i*64+r, o] = relu( A1'[b*64+r, o] + sum_{t<8} W1br[o][t]*x_bi[r*8+t] )
//     A1' = input_flat @ W1a^T + b1  (k_conv tail: bf16 MFMA, C-frag out)
//   h LDS layout (fp8): elem (tile T, r, c) at
//     T*32768 + r*512 + (((c>>3) ^ (r&7))<<3) + (c&7)                 [bytes]
//   Weight layout (fp8, K=128 frag-major): elem (o,k) at
//     (o>>4)*8192 + (k>>7)*2048 + (((k>>5)&3)*16 + (o&15))*32 + (k&31) [bytes]
// ---------------------------------------------------------------------------

typedef float f32x4 __attribute__((ext_vector_type(4)));
typedef __bf16 bf16x8v __attribute__((ext_vector_type(8)));
typedef int i32x8 __attribute__((ext_vector_type(8)));
typedef long i64;

__device__ __forceinline__ unsigned cvt4_fp8(float a, float b, float c, float d) {
  unsigned v = 0;
  v = __builtin_amdgcn_cvt_pk_fp8_f32(a, b, v, false);
  v = __builtin_amdgcn_cvt_pk_fp8_f32(c, d, v, true);
  return v;
}

// workspace byte offsets
#define WS_A1Q     0u           // 16 x 128 x 64 float4 = 2 MB  (A1+b1, C-frag layout)
#define WS_W1P     2097152u     // 512 x 32 bf16 = 32 KB (W1br zero-padded, A-swizzle)
#define WS_SENT    2129920u     // 16*512 f32 = 32 KB
#define WS_Y       2162688u     // 16*512 f32 = 32 KB (im-linear y)
#define WS_IMGEMB  2195456u     // 16*512 f32 = 32 KB
#define WS_W2F8    2228224u     // 512*512 fp8 = 256 KB (frag-major)
#define WS_W3F8    2490368u     // 512*512 fp8 = 256 KB (frag-major)
// total ~2.75 MB

// ---------------------------------------------------------------------------
// k_conv (848 blocks x 256 thr):
//   0..255    : W2 / W3 -> fp8 e4m3 frag-major (K=128 fragments)
//   256..271  : W1br -> bf16 A-swizzle (K=32 pad) + sent zero
//   272..783  : im-linear y = im_input @ im_w^T + im_b
//   784..847  : A1' = input_flat @ W1a^T + b1 (bf16 MFMA, direct fp32 W1a reads)
// ---------------------------------------------------------------------------
__global__ __launch_bounds__(256) void k_conv(
    const float* __restrict__ input, const float* __restrict__ im_input,
    const float* __restrict__ g1w, const float* __restrict__ g1b,
    const float* __restrict__ g2w, const float* __restrict__ g3w,
    const float* __restrict__ imw, const float* __restrict__ imb,
    float* __restrict__ ws)
{
  __shared__ __align__(16) __bf16 xbuf[32768];   // 64x512 bf16, swizzled (A1 blocks)
  const int blk = blockIdx.x, t = threadIdx.x;
  __bf16* w1p  = (__bf16*)((char*)ws + WS_W1P);
  float* sent  = (float*)((char*)ws + WS_SENT);
  float* yv    = (float*)((char*)ws + WS_Y);
  unsigned char* w2f8 = (unsigned char*)ws + WS_W2F8;
  unsigned char* w3f8 = (unsigned char*)ws + WS_W3F8;
  float* A1Qf = ws;

  if (blk < 256) {
    // W2 / W3 -> fp8 frag-major
    int idx = (blk * 256 + t) * 8;            // 0..524288-8
    const float* src; unsigned char* dst; int off;
    if (idx < 262144) { src = g2w; dst = w2f8; off = idx; }
    else              { src = g3w; dst = w3f8; off = idx - 262144; }
    int o = off >> 9, k = off & 511;
    int doff = (o >> 4) * 8192 + (k >> 7) * 2048 + (((k >> 5) & 3) * 16 + (o & 15)) * 32 + (k & 31);
    float4 v0 = *(const float4*)(src + off);
    float4 v1 = *(const float4*)(src + off + 4);
    uint2 pk;
    pk.x = cvt4_fp8(v0.x, v0.y, v0.z, v0.w);
    pk.y = cvt4_fp8(v1.x, v1.y, v1.z, v1.w);
    *(uint2*)(dst + doff) = pk;
  } else if (blk < 272) {
    // W1P[o][s] = sum_{u<64} gmlp1_w[o][512 + s*64 + u], bf16, A-swizzle, K=32 pad
    int idx = (blk - 256) * 256 + t;      // 0..4095
    int o = idx >> 3, s = idx & 7;
    const float* p = g1w + (size_t)o * 1024 + 512 + s * 64;
    float sum = 0.f;
#pragma unroll
    for (int u = 0; u < 64; u += 4) {
      float4 v = *(const float4*)(p + u);
      sum += v.x + v.y + v.z + v.w;
    }
    int base = (o >> 4) * 512 + (o & 15) * 8 + s;   // quad 0 slot
    w1p[base]       = (__bf16)sum;
    w1p[base + 128] = (__bf16)0.f;                  // quads 1..3 = zero pad
    w1p[base + 256] = (__bf16)0.f;
    w1p[base + 384] = (__bf16)0.f;
    sent[idx] = 0.f; sent[idx + 4096] = 0.f;        // zero accumulator
  } else if (blk < 784) {
    // y[b][o] = dot(im_input[b], im_w[o]) + im_b[o]; one block per o
    int o = blk - 272;                    // 0..511
    int wv = t >> 6, l = t & 63;
    const float* wrow = imw + (size_t)o * 2048;
    for (int bb = 0; bb < 4; ++bb) {
      int b = wv * 4 + bb;
      const float* xr = im_input + (size_t)b * 2048;
      float s = 0.f;
#pragma unroll
      for (int u = 0; u < 8; ++u) {
        int k = u * 256 + l * 4;
        float4 xv = *(const float4*)(xr + k);
        float4 wx = *(const float4*)(wrow + k);
        s += xv.x * wx.x + xv.y * wx.y + xv.z * wx.z + xv.w * wx.w;
      }
#pragma unroll
      for (int m = 32; m >= 1; m >>= 1) s += __shfl_xor(s, m);
      if (l == 0) yv[b * 512 + o] = s + imb[o];
    }
  } else {
    // A1' GEMM: 64 blocks = (b, o-quarter q). Wave w: o-span q*128 + w*32.
    int pb = blk - 784;
    int b = pb >> 2, q = pb & 3;
#pragma unroll
    for (int it = 0; it < 16; ++it) {
      int id = t + 256 * it;
      int r = id >> 6, oc = id & 63;
      const float* src = input + (size_t)(b * 64 + r) * 512 + oc * 8;
      float4 v0 = *(const float4*)src;
      float4 v1 = *(const float4*)(src + 4);
      bf16x8v h;
      h[0] = (__bf16)v0.x; h[1] = (__bf16)v0.y; h[2] = (__bf16)v0.z; h[3] = (__bf16)v0.w;
      h[4] = (__bf16)v1.x; h[5] = (__bf16)v1.y; h[6] = (__bf16)v1.z; h[7] = (__bf16)v1.w;
      *(bf16x8v*)(xbuf + r * 512 + ((oc ^ (r & 7)) << 3)) = h;
    }
    __syncthreads();
    const int w = t >> 6, l = t & 63;
    const int quad = l >> 4, p16 = l & 15;
    const int msk3 = (p16 & 7) << 3;
    f32x4 acc2[2][4];
#pragma unroll
    for (int ot = 0; ot < 2; ++ot)
#pragma unroll
      for (int mt = 0; mt < 4; ++mt) { f32x4 z = {0.f, 0.f, 0.f, 0.f}; acc2[ot][mt] = z; }
    const float* wbase = g1w + (size_t)(q * 128 + w * 32 + p16) * 1024;
#pragma unroll 2
    for (int ks = 0; ks < 16; ++ks) {
      const int kcb = (((ks * 4 + quad) << 3) ^ msk3);
      bf16x8v bf[4];
#pragma unroll
      for (int mt = 0; mt < 4; ++mt)
        bf[mt] = *(const bf16x8v*)(xbuf + (p16 + 16 * mt) * 512 + kcb);
#pragma unroll
      for (int ot = 0; ot < 2; ++ot) {
        const float* ap = wbase + ot * 16384 + ks * 32 + quad * 8;
        float4 f0 = *(const float4*)ap;
        float4 f1 = *(const float4*)(ap + 4);
        bf16x8v af;
        af[0] = (__bf16)f0.x; af[1] = (__bf16)f0.y; af[2] = (__bf16)f0.z; af[3] = (__bf16)f0.w;
        af[4] = (__bf16)f1.x; af[5] = (__bf16)f1.y; af[6] = (__bf16)f1.z; af[7] = (__bf16)f1.w;
#pragma unroll
        for (int mt = 0; mt < 4; ++mt)
          acc2[ot][mt] = __builtin_amdgcn_mfma_f32_16x16x32_bf16(af, bf[mt], acc2[ot][mt], 0, 0, 0);
      }
    }
#pragma unroll
    for (int ot = 0; ot < 2; ++ot) {
      int o = q * 128 + w * 32 + ot * 16 + quad * 4;
      float4 bias = *(const float4*)(g1b + o);
      float bb[4] = {bias.x, bias.y, bias.z, bias.w};
      size_t o4 = (size_t)b * 128 + (o >> 2);
#pragma unroll
      for (int mt = 0; mt < 4; ++mt)
#pragma unroll
        for (int r = 0; r < 4; ++r)
          A1Qf[(o4 * 64 + mt * 16 + p16) * 4 + r] = acc2[ot][mt][r] + bb[r];
    }
  }
}

// ---------------------------------------------------------------------------
// K=128 scaled-fp8 transposed-GEMM K-loop, two-tile (M=128).
// 4 k-steps; per step: 4 A-frags (2 x 16 B, natural k) x 8 B-frags (4 x b64
// via chunk-XOR addresses — identical LDS pattern to R10). Unit E8M0 scales.
// ---------------------------------------------------------------------------
__device__ __forceinline__ void kloop128(const unsigned char* __restrict__ wl,
                                         const unsigned char* __restrict__ hbuf,
                                         int p16, int quad, f32x4 acc[4][8])
{
  const int msk = p16 & 7;
  int moff[8];
#pragma unroll
  for (int mt = 0; mt < 8; ++mt)
    moff[mt] = (mt >> 2) * 32768 + (p16 + 16 * (mt & 3)) * 512;
  i32x8 a[2][4];
#pragma unroll
  for (int ot = 0; ot < 4; ++ot) {
    union { i32x8 v; uint4 q[2]; } ua;
    ua.q[0] = *(const uint4*)(wl + ot * 8192);
    ua.q[1] = *(const uint4*)(wl + ot * 8192 + 16);
    a[0][ot] = ua.v;
  }
#pragma unroll
  for (int ks = 0; ks < 4; ++ks) {
    const int cur = ks & 1, nxt = cur ^ 1;
    const int cb = ks * 16 + quad * 4;
    // B half 1 (tile 0 rows)
    i32x8 bf[4];
#pragma unroll
    for (int mt = 0; mt < 4; ++mt) {
      union { i32x8 v; i64 d[4]; } u;
#pragma unroll
      for (int dd = 0; dd < 4; ++dd)
        u.d[dd] = *(const i64*)(hbuf + moff[mt] + (((cb + dd) ^ msk) << 3));
      bf[mt] = u.v;
    }
    // prefetch next-ks A-frags
    if (ks < 3) {
#pragma unroll
      for (int ot = 0; ot < 4; ++ot) {
        union { i32x8 v; uint4 q[2]; } ua;
        ua.q[0] = *(const uint4*)(wl + (ks + 1) * 2048 + ot * 8192);
        ua.q[1] = *(const uint4*)(wl + (ks + 1) * 2048 + ot * 8192 + 16);
        a[nxt][ot] = ua.v;
      }
    }
#pragma unroll
    for (int ot = 0; ot < 4; ++ot)
#pragma unroll
      for (int mt = 0; mt < 4; ++mt)
        acc[ot][mt] = __builtin_amdgcn_mfma_scale_f32_16x16x128_f8f6f4(
            a[cur][ot], bf[mt], acc[ot][mt], 0, 0, 0, 0x7F7F7F7F, 0, 0x7F7F7F7F);
    // B half 2 (tile 1 rows)
#pragma unroll
    for (int mt = 0; mt < 4; ++mt) {
      union { i32x8 v; i64 d[4]; } u;
#pragma unroll
      for (int dd = 0; dd < 4; ++dd)
        u.d[dd] = *(const i64*)(hbuf + moff[mt + 4] + (((cb + dd) ^ msk) << 3));
      bf[mt] = u.v;
    }
#pragma unroll
    for (int ot = 0; ot < 4; ++ot)
#pragma unroll
      for (int mt = 0; mt < 4; ++mt)
        acc[ot][mt + 4] = __builtin_amdgcn_mfma_scale_f32_16x16x128_f8f6f4(
            a[cur][ot], bf[mt], acc[ot][mt + 4], 0, 0, 0, 0x7F7F7F7F, 0, 0x7F7F7F7F);
  }
}

// ---------------------------------------------------------------------------
// Main fused kernel: blocks 0..511 = (b, i-pair) tiles (512 thr, 8 waves,
// two 32 KB fp8 LDS h-buffers); block 512 = BatchNorm.
// Wave w covers o in [w*64, w*64+64) via 4 ot; mt 0..3 = tile0, 4..7 = tile1.
// ---------------------------------------------------------------------------
__global__ __launch_bounds__(512, 2) void k_main(
    const float* __restrict__ input,
    const float* __restrict__ g2b, const float* __restrict__ g3b,
    const float* __restrict__ bng, const float* __restrict__ bnb,
    float* __restrict__ ws)
{
  const int blk = blockIdx.x, t = threadIdx.x;
  const float4* A1Q = (const float4*)ws;
  const __bf16* w1p = (const __bf16*)((char*)ws + WS_W1P);
  float* sent = (float*)((char*)ws + WS_SENT);
  float* yv   = (float*)((char*)ws + WS_Y);
  float* imge = (float*)((char*)ws + WS_IMGEMB);
  const unsigned char* w2f8 = (const unsigned char*)ws + WS_W2F8;
  const unsigned char* w3f8 = (const unsigned char*)ws + WS_W3F8;

  if (blk == 512) {
    // BatchNorm1d (training-mode batch stats) + ReLU over y[16][512]
    int o = t;
    float vals[16];
    float mu = 0.f;
#pragma unroll
    for (int b = 0; b < 16; ++b) { vals[b] = yv[b * 512 + o]; mu += vals[b]; }
    mu *= (1.f / 16.f);
    float var = 0.f;
#pragma unroll
    for (int b = 0; b < 16; ++b) { float d = vals[b] - mu; var += d * d; }
    var *= (1.f / 16.f);
    float sc = bng[o] * rsqrtf(var + 1e-5f);
    float sh = bnb[o] - mu * sc;
#pragma unroll
    for (int b = 0; b < 16; ++b)
      imge[b * 512 + o] = fmaxf(vals[b] * sc + sh, 0.f);
    return;
  }

  // two swizzled 64x512 fp8 h-buffers = 64 KB
  __shared__ __align__(16) unsigned char hbuf8[65536];

  const int b = blk >> 5, ipair = blk & 31;
  const int w = t >> 6, l = t & 63;
  const int quad = l >> 4, p16 = l & 15;

  // x rows for both tiles: lane l holds x[l*8 .. l*8+7]
  float xreg0[8], xreg1[8];
  {
    const float* xr0 = input + (size_t)(b * 64 + ipair * 2) * 512 + l * 8;
    *(float4*)xreg0       = *(const float4*)xr0;
    *(float4*)(xreg0 + 4) = *(const float4*)(xr0 + 4);
    *(float4*)xreg1       = *(const float4*)(xr0 + 512);
    *(float4*)(xreg1 + 4) = *(const float4*)(xr0 + 516);
  }

  f32x4 acc[4][8];

  // ---- phase 1: h1 = relu(A1' + W1br @ x), bf16 MFMA, both tiles -> fp8 LDS ----
  {
    bf16x8v xb[8];
#pragma unroll
    for (int mt = 0; mt < 4; ++mt) {
#pragma unroll
      for (int j = 0; j < 8; ++j) {
        float v0 = __shfl(xreg0[j], p16 + 16 * mt);
        float v1 = __shfl(xreg1[j], p16 + 16 * mt);
        xb[mt][j]     = (quad == 0) ? (__bf16)v0 : (__bf16)0.f;
        xb[mt + 4][j] = (quad == 0) ? (__bf16)v1 : (__bf16)0.f;
      }
    }
#pragma unroll
    for (int ot = 0; ot < 4; ++ot)
#pragma unroll
      for (int mt = 0; mt < 8; ++mt) { f32x4 z = {0.f, 0.f, 0.f, 0.f}; acc[ot][mt] = z; }
#pragma unroll
    for (int ot = 0; ot < 4; ++ot) {
      bf16x8v af = *(const bf16x8v*)(w1p + (w * 4 + ot) * 512 + l * 8);
#pragma unroll
      for (int mt = 0; mt < 8; ++mt)
        acc[ot][mt] = __builtin_amdgcn_mfma_f32_16x16x32_bf16(af, xb[mt], acc[ot][mt], 0, 0, 0);
    }
    const float4* cq = A1Q + ((size_t)b * 128 + w * 16) * 64;
#pragma unroll
    for (int ot = 0; ot < 4; ++ot) {
#pragma unroll
      for (int mtp = 0; mtp < 4; ++mtp) {
        float4 c = cq[(ot * 4 + quad) * 64 + 16 * mtp + p16];
        int row = p16 + 16 * mtp;
        int col = w * 64 + ot * 16 + quad * 4;
        int addr = row * 512 + (((col >> 3) ^ (row & 7)) << 3) + (col & 7);
#pragma unroll
        for (int tau = 0; tau < 2; ++tau) {
          f32x4 v = acc[ot][tau * 4 + mtp];
          unsigned pk = cvt4_fp8(fmaxf(v[0] + c.x, 0.f), fmaxf(v[1] + c.y, 0.f),
                                 fmaxf(v[2] + c.z, 0.f), fmaxf(v[3] + c.w, 0.f));
          *(unsigned*)(hbuf8 + tau * 32768 + addr) = pk;
        }
      }
    }
  }
  __syncthreads();

  // ---- phase 2: h2 = relu(h1 @ W2^T + b2), K=128 scaled fp8 ----
#pragma unroll
  for (int ot = 0; ot < 4; ++ot)
#pragma unroll
    for (int mt = 0; mt < 8; ++mt) { f32x4 z = {0.f, 0.f, 0.f, 0.f}; acc[ot][mt] = z; }

  kloop128(w2f8 + (size_t)(w * 4) * 8192 + l * 32, hbuf8, p16, quad, acc);
  __syncthreads();  // all h1 reads done before overwrite
#pragma unroll
  for (int ot = 0; ot < 4; ++ot) {
    float4 b2 = *(const float4*)(g2b + w * 64 + ot * 16 + quad * 4);
#pragma unroll
    for (int mt = 0; mt < 8; ++mt) {
      f32x4 v = acc[ot][mt];
      unsigned pk = cvt4_fp8(fmaxf(v[0] + b2.x, 0.f), fmaxf(v[1] + b2.y, 0.f),
                             fmaxf(v[2] + b2.z, 0.f), fmaxf(v[3] + b2.w, 0.f));
      int row = p16 + 16 * (mt & 3);
      int col = w * 64 + ot * 16 + quad * 4;
      *(unsigned*)(hbuf8 + (mt >> 2) * 32768 + row * 512 +
                   (((col >> 3) ^ (row & 7)) << 3) + (col & 7)) = pk;
    }
  }
  __syncthreads();

  // ---- phase 3: h3 = relu(h2 @ W3^T + b3), K=128 scaled fp8, fused mean ----
#pragma unroll
  for (int ot = 0; ot < 4; ++ot)
#pragma unroll
    for (int mt = 0; mt < 8; ++mt) { f32x4 z = {0.f, 0.f, 0.f, 0.f}; acc[ot][mt] = z; }

  kloop128(w3f8 + (size_t)(w * 4) * 8192 + l * 32, hbuf8, p16, quad, acc);

#pragma unroll
  for (int ot = 0; ot < 4; ++ot) {
    float4 b3 = *(const float4*)(g3b + w * 64 + ot * 16 + quad * 4);
    float bb[4] = {b3.x, b3.y, b3.z, b3.w};
#pragma unroll
    for (int r = 0; r < 4; ++r) {
      float s = 0.f;
#pragma unroll
      for (int mt = 0; mt < 8; ++mt) s += fmaxf(acc[ot][mt][r] + bb[r], 0.f);
      s += __shfl_xor(s, 1);
      s += __shfl_xor(s, 2);
      s += __shfl_xor(s, 4);
      s += __shfl_xor(s, 8);
      if (p16 == 0)
        atomicAdd(&sent[b * 512 + w * 64 + ot * 16 + quad * 4 + r], s * (1.0f / 4096.0f));
    }
  }
}

// ---------------------------------------------------------------------------
// Head: one block per b (512 thr, 8 waves). Wave v: rows v*64..v*64+63,
// wave-cooperative coalesced d1w reads, butterfly reduce, LDS cross-wave
// reduce, direct store.
// ---------------------------------------------------------------------------
__global__ __launch_bounds__(512) void k_head(
    const float* __restrict__ d1w, const float* __restrict__ d1b,
    const float* __restrict__ d2w, const float* __restrict__ d2b,
    const float* __restrict__ ws, float* __restrict__ out)
{
  __shared__ float emb[1024];
  __shared__ float red[8][2];
  const float* sent = (const float*)((const char*)ws + WS_SENT);
  const float* imge = (const float*)((const char*)ws + WS_IMGEMB);
  const int b = blockIdx.x, t = threadIdx.x;
  emb[t]       = sent[b * 512 + t];
  emb[512 + t] = imge[b * 512 + t];
  __syncthreads();
  const int v = t >> 6, l = t & 63;
  float p0 = 0.f, p1 = 0.f;
  for (int rr = 0; rr < 64; ++rr) {
    int row = v * 64 + rr;
    const float* wr = d1w + (size_t)row * 1024 + l * 4;
    float s = 0.f;
#pragma unroll
    for (int c = 0; c < 4; ++c) {
      float4 wv = *(const float4*)(wr + c * 256);
      float4 ev = *(const float4*)(emb + l * 4 + c * 256);
      s += wv.x * ev.x + wv.y * ev.y + wv.z * ev.z + wv.w * ev.w;
    }
#pragma unroll
    for (int m = 32; m >= 1; m >>= 1) s += __shfl_xor(s, m);
    float h = fmaxf(s + d1b[row], 0.f);
    p0 += d2w[row] * h;
    p1 += d2w[512 + row] * h;
  }
  if (l == 0) { red[v][0] = p0; red[v][1] = p1; }
  __syncthreads();
  if (t == 0) {
    float q0 = d2b[0], q1 = d2b[1];
#pragma unroll
    for (int u = 0; u < 8; ++u) { q0 += red[u][0]; q1 += red[u][1]; }
    out[b * 2 + 0] = q0;
    out[b * 2 + 1] = q1;
  }
}

// ---------------------------------------------------------------------------
extern "C" void kernel_launch(void* const* d_in, const int* in_sizes, int n_in,
                              void* d_out, int out_size, void* d_ws, size_t ws_size,
                              hipStream_t stream)
{
  const float* input    = (const float*)d_in[0];
  const float* im_input = (const float*)d_in[1];
  const float* g1w = (const float*)d_in[2];
  const float* g1b = (const float*)d_in[3];
  const float* g2w = (const float*)d_in[4];
  const float* g2b = (const float*)d_in[5];
  const float* g3w = (const float*)d_in[6];
  const float* g3b = (const float*)d_in[7];
  const float* imw = (const float*)d_in[8];
  const float* imb = (const float*)d_in[9];
  const float* bng = (const float*)d_in[10];
  const float* bnb = (const float*)d_in[11];
  const float* d1w = (const float*)d_in[12];
  const float* d1b = (const float*)d_in[13];
  const float* d2w = (const float*)d_in[14];
  const float* d2b = (const float*)d_in[15];
  float* out = (float*)d_out;
  float* ws  = (float*)d_ws;

  k_conv<<<848, 256, 0, stream>>>(input, im_input, g1w, g1b, g2w, g3w, imw, imb, ws);
  k_main<<<513, 512, 0, stream>>>(input, g2b, g3b, bng, bnb, ws);
  k_head<<<16, 512, 0, stream>>>(d1w, d1b, d2w, d2b, ws, out);
}

// Round 12
// 263.174 us; speedup vs baseline: 1.0127x; 1.0127x over previous
//
#include <hip/hip_runtime.h>

// ---------------------------------------------------------------------------
// Discriminator fused pipeline for MI355X (gfx950).
// R12: K=128 block-scaled fp8 MFMA (unit scales — numerics verified in R11)
// with REGISTER-LEAN kloop: sequential B-fragments (8 VGPR live), A ping-pong
// (64 VGPR), acc 128 AGPR -> ~233 regs, under the 256 cap (R11 spilled at
// >256: FETCH 222 MB scratch traffic; this round removes the spill).
//
//   h1[b, i*64+r, o] = relu( A1'[b*64+r, o] + sum_{t<8} W1br[o][t]*x_bi[r*8+t] )
//     A1' = input_flat @ W1a^T + b1  (k_conv tail: bf16 MFMA, C-frag out)
//   h LDS layout (fp8): elem (tile T, r, c) at
//     T*32768 + r*512 + (((c>>3) ^ (r&7))<<3) + (c&7)                 [bytes]
//   Weight layout (fp8, K=128 frag-major): elem (o,k) at
//     (o>>4)*8192 + (k>>7)*2048 + (((k>>5)&3)*16 + (o&15))*32 + (k&31) [bytes]
// ---------------------------------------------------------------------------

typedef float f32x4 __attribute__((ext_vector_type(4)));
typedef __bf16 bf16x8v __attribute__((ext_vector_type(8)));
typedef int i32x8 __attribute__((ext_vector_type(8)));
typedef long i64;

__device__ __forceinline__ unsigned cvt4_fp8(float a, float b, float c, float d) {
  unsigned v = 0;
  v = __builtin_amdgcn_cvt_pk_fp8_f32(a, b, v, false);
  v = __builtin_amdgcn_cvt_pk_fp8_f32(c, d, v, true);
  return v;
}

// workspace byte offsets
#define WS_A1Q     0u           // 16 x 128 x 64 float4 = 2 MB  (A1+b1, C-frag layout)
#define WS_W1P     2097152u     // 512 x 32 bf16 = 32 KB (W1br zero-padded, A-swizzle)
#define WS_SENT    2129920u     // 16*512 f32 = 32 KB
#define WS_Y       2162688u     // 16*512 f32 = 32 KB (im-linear y)
#define WS_IMGEMB  2195456u     // 16*512 f32 = 32 KB
#define WS_W2F8    2228224u     // 512*512 fp8 = 256 KB (frag-major)
#define WS_W3F8    2490368u     // 512*512 fp8 = 256 KB (frag-major)
// total ~2.75 MB

// ---------------------------------------------------------------------------
// k_conv (848 blocks x 256 thr):
//   0..255    : W2 / W3 -> fp8 e4m3 frag-major (K=128 fragments)
//   256..271  : W1br -> bf16 A-swizzle (K=32 pad) + sent zero
//   272..783  : im-linear y = im_input @ im_w^T + im_b
//   784..847  : A1' = input_flat @ W1a^T + b1 (bf16 MFMA, direct fp32 W1a reads)
// ---------------------------------------------------------------------------
__global__ __launch_bounds__(256) void k_conv(
    const float* __restrict__ input, const float* __restrict__ im_input,
    const float* __restrict__ g1w, const float* __restrict__ g1b,
    const float* __restrict__ g2w, const float* __restrict__ g3w,
    const float* __restrict__ imw, const float* __restrict__ imb,
    float* __restrict__ ws)
{
  __shared__ __align__(16) __bf16 xbuf[32768];   // 64x512 bf16, swizzled (A1 blocks)
  const int blk = blockIdx.x, t = threadIdx.x;
  __bf16* w1p  = (__bf16*)((char*)ws + WS_W1P);
  float* sent  = (float*)((char*)ws + WS_SENT);
  float* yv    = (float*)((char*)ws + WS_Y);
  unsigned char* w2f8 = (unsigned char*)ws + WS_W2F8;
  unsigned char* w3f8 = (unsigned char*)ws + WS_W3F8;
  float* A1Qf = ws;

  if (blk < 256) {
    // W2 / W3 -> fp8 frag-major
    int idx = (blk * 256 + t) * 8;            // 0..524288-8
    const float* src; unsigned char* dst; int off;
    if (idx < 262144) { src = g2w; dst = w2f8; off = idx; }
    else              { src = g3w; dst = w3f8; off = idx - 262144; }
    int o = off >> 9, k = off & 511;
    int doff = (o >> 4) * 8192 + (k >> 7) * 2048 + (((k >> 5) & 3) * 16 + (o & 15)) * 32 + (k & 31);
    float4 v0 = *(const float4*)(src + off);
    float4 v1 = *(const float4*)(src + off + 4);
    uint2 pk;
    pk.x = cvt4_fp8(v0.x, v0.y, v0.z, v0.w);
    pk.y = cvt4_fp8(v1.x, v1.y, v1.z, v1.w);
    *(uint2*)(dst + doff) = pk;
  } else if (blk < 272) {
    // W1P[o][s] = sum_{u<64} gmlp1_w[o][512 + s*64 + u], bf16, A-swizzle, K=32 pad
    int idx = (blk - 256) * 256 + t;      // 0..4095
    int o = idx >> 3, s = idx & 7;
    const float* p = g1w + (size_t)o * 1024 + 512 + s * 64;
    float sum = 0.f;
#pragma unroll
    for (int u = 0; u < 64; u += 4) {
      float4 v = *(const float4*)(p + u);
      sum += v.x + v.y + v.z + v.w;
    }
    int base = (o >> 4) * 512 + (o & 15) * 8 + s;   // quad 0 slot
    w1p[base]       = (__bf16)sum;
    w1p[base + 128] = (__bf16)0.f;                  // quads 1..3 = zero pad
    w1p[base + 256] = (__bf16)0.f;
    w1p[base + 384] = (__bf16)0.f;
    sent[idx] = 0.f; sent[idx + 4096] = 0.f;        // zero accumulator
  } else if (blk < 784) {
    // y[b][o] = dot(im_input[b], im_w[o]) + im_b[o]; one block per o
    int o = blk - 272;                    // 0..511
    int wv = t >> 6, l = t & 63;
    const float* wrow = imw + (size_t)o * 2048;
    for (int bb = 0; bb < 4; ++bb) {
      int b = wv * 4 + bb;
      const float* xr = im_input + (size_t)b * 2048;
      float s = 0.f;
#pragma unroll
      for (int u = 0; u < 8; ++u) {
        int k = u * 256 + l * 4;
        float4 xv = *(const float4*)(xr + k);
        float4 wx = *(const float4*)(wrow + k);
        s += xv.x * wx.x + xv.y * wx.y + xv.z * wx.z + xv.w * wx.w;
      }
#pragma unroll
      for (int m = 32; m >= 1; m >>= 1) s += __shfl_xor(s, m);
      if (l == 0) yv[b * 512 + o] = s + imb[o];
    }
  } else {
    // A1' GEMM: 64 blocks = (b, o-quarter q). Wave w: o-span q*128 + w*32.
    int pb = blk - 784;
    int b = pb >> 2, q = pb & 3;
#pragma unroll
    for (int it = 0; it < 16; ++it) {
      int id = t + 256 * it;
      int r = id >> 6, oc = id & 63;
      const float* src = input + (size_t)(b * 64 + r) * 512 + oc * 8;
      float4 v0 = *(const float4*)src;
      float4 v1 = *(const float4*)(src + 4);
      bf16x8v h;
      h[0] = (__bf16)v0.x; h[1] = (__bf16)v0.y; h[2] = (__bf16)v0.z; h[3] = (__bf16)v0.w;
      h[4] = (__bf16)v1.x; h[5] = (__bf16)v1.y; h[6] = (__bf16)v1.z; h[7] = (__bf16)v1.w;
      *(bf16x8v*)(xbuf + r * 512 + ((oc ^ (r & 7)) << 3)) = h;
    }
    __syncthreads();
    const int w = t >> 6, l = t & 63;
    const int quad = l >> 4, p16 = l & 15;
    const int msk3 = (p16 & 7) << 3;
    f32x4 acc2[2][4];
#pragma unroll
    for (int ot = 0; ot < 2; ++ot)
#pragma unroll
      for (int mt = 0; mt < 4; ++mt) { f32x4 z = {0.f, 0.f, 0.f, 0.f}; acc2[ot][mt] = z; }
    const float* wbase = g1w + (size_t)(q * 128 + w * 32 + p16) * 1024;
#pragma unroll 2
    for (int ks = 0; ks < 16; ++ks) {
      const int kcb = (((ks * 4 + quad) << 3) ^ msk3);
      bf16x8v bf[4];
#pragma unroll
      for (int mt = 0; mt < 4; ++mt)
        bf[mt] = *(const bf16x8v*)(xbuf + (p16 + 16 * mt) * 512 + kcb);
#pragma unroll
      for (int ot = 0; ot < 2; ++ot) {
        const float* ap = wbase + ot * 16384 + ks * 32 + quad * 8;
        float4 f0 = *(const float4*)ap;
        float4 f1 = *(const float4*)(ap + 4);
        bf16x8v af;
        af[0] = (__bf16)f0.x; af[1] = (__bf16)f0.y; af[2] = (__bf16)f0.z; af[3] = (__bf16)f0.w;
        af[4] = (__bf16)f1.x; af[5] = (__bf16)f1.y; af[6] = (__bf16)f1.z; af[7] = (__bf16)f1.w;
#pragma unroll
        for (int mt = 0; mt < 4; ++mt)
          acc2[ot][mt] = __builtin_amdgcn_mfma_f32_16x16x32_bf16(af, bf[mt], acc2[ot][mt], 0, 0, 0);
      }
    }
#pragma unroll
    for (int ot = 0; ot < 2; ++ot) {
      int o = q * 128 + w * 32 + ot * 16 + quad * 4;
      float4 bias = *(const float4*)(g1b + o);
      float bb[4] = {bias.x, bias.y, bias.z, bias.w};
      size_t o4 = (size_t)b * 128 + (o >> 2);
#pragma unroll
      for (int mt = 0; mt < 4; ++mt)
#pragma unroll
        for (int r = 0; r < 4; ++r)
          A1Qf[(o4 * 64 + mt * 16 + p16) * 4 + r] = acc2[ot][mt][r] + bb[r];
    }
  }
}

// ---------------------------------------------------------------------------
// K=128 scaled-fp8 K-loop, REGISTER-LEAN: A ping-pong (a[2][4], 64 VGPR),
// B-fragments built & consumed one at a time (8 VGPR live; each feeds 4
// MFMAs). Next-step A loads issue between the two tile halves (16 MFMAs of
// cover). LDS access pattern identical to R10 (4 x b64, chunk-XOR).
// ---------------------------------------------------------------------------
__device__ __forceinline__ void kloop128(const unsigned char* __restrict__ wl,
                                         const unsigned char* __restrict__ hbuf,
                                         int p16, int quad, f32x4 acc[4][8])
{
  const int msk = p16 & 7;
  int moff[8];
#pragma unroll
  for (int mt = 0; mt < 8; ++mt)
    moff[mt] = (mt >> 2) * 32768 + (p16 + 16 * (mt & 3)) * 512;
  i32x8 a[2][4];
#pragma unroll
  for (int ot = 0; ot < 4; ++ot) {
    union { i32x8 v; uint4 q[2]; } ua;
    ua.q[0] = *(const uint4*)(wl + ot * 8192);
    ua.q[1] = *(const uint4*)(wl + ot * 8192 + 16);
    a[0][ot] = ua.v;
  }
#pragma unroll
  for (int ks = 0; ks < 4; ++ks) {
    const int cur = ks & 1, nxt = cur ^ 1;
    const int cb = ks * 16 + quad * 4;
    // tile 0: one B-frag at a time -> 4 MFMAs each
#pragma unroll
    for (int mt = 0; mt < 4; ++mt) {
      union { i32x8 v; i64 d[4]; } u;
#pragma unroll
      for (int dd = 0; dd < 4; ++dd)
        u.d[dd] = *(const i64*)(hbuf + moff[mt] + (((cb + dd) ^ msk) << 3));
#pragma unroll
      for (int ot = 0; ot < 4; ++ot)
        acc[ot][mt] = __builtin_amdgcn_mfma_scale_f32_16x16x128_f8f6f4(
            a[cur][ot], u.v, acc[ot][mt], 0, 0, 0, 0x7F7F7F7F, 0, 0x7F7F7F7F);
    }
    // prefetch next-step A while tile-1 MFMAs execute
    if (ks < 3) {
#pragma unroll
      for (int ot = 0; ot < 4; ++ot) {
        union { i32x8 v; uint4 q[2]; } ua;
        ua.q[0] = *(const uint4*)(wl + (ks + 1) * 2048 + ot * 8192);
        ua.q[1] = *(const uint4*)(wl + (ks + 1) * 2048 + ot * 8192 + 16);
        a[nxt][ot] = ua.v;
      }
    }
    // tile 1
#pragma unroll
    for (int mt = 0; mt < 4; ++mt) {
      union { i32x8 v; i64 d[4]; } u;
#pragma unroll
      for (int dd = 0; dd < 4; ++dd)
        u.d[dd] = *(const i64*)(hbuf + moff[mt + 4] + (((cb + dd) ^ msk) << 3));
#pragma unroll
      for (int ot = 0; ot < 4; ++ot)
        acc[ot][mt + 4] = __builtin_amdgcn_mfma_scale_f32_16x16x128_f8f6f4(
            a[cur][ot], u.v, acc[ot][mt + 4], 0, 0, 0, 0x7F7F7F7F, 0, 0x7F7F7F7F);
    }
  }
}

// ---------------------------------------------------------------------------
// Main fused kernel: blocks 0..511 = (b, i-pair) tiles (512 thr, 8 waves,
// two 32 KB fp8 LDS h-buffers); block 512 = BatchNorm.
// Wave w covers o in [w*64, w*64+64) via 4 ot; mt 0..3 = tile0, 4..7 = tile1.
// ---------------------------------------------------------------------------
__global__ __launch_bounds__(512, 2) void k_main(
    const float* __restrict__ input,
    const float* __restrict__ g2b, const float* __restrict__ g3b,
    const float* __restrict__ bng, const float* __restrict__ bnb,
    float* __restrict__ ws)
{
  const int blk = blockIdx.x, t = threadIdx.x;
  const float4* A1Q = (const float4*)ws;
  const __bf16* w1p = (const __bf16*)((char*)ws + WS_W1P);
  float* sent = (float*)((char*)ws + WS_SENT);
  float* yv   = (float*)((char*)ws + WS_Y);
  float* imge = (float*)((char*)ws + WS_IMGEMB);
  const unsigned char* w2f8 = (const unsigned char*)ws + WS_W2F8;
  const unsigned char* w3f8 = (const unsigned char*)ws + WS_W3F8;

  if (blk == 512) {
    // BatchNorm1d (training-mode batch stats) + ReLU over y[16][512]
    int o = t;
    float vals[16];
    float mu = 0.f;
#pragma unroll
    for (int b = 0; b < 16; ++b) { vals[b] = yv[b * 512 + o]; mu += vals[b]; }
    mu *= (1.f / 16.f);
    float var = 0.f;
#pragma unroll
    for (int b = 0; b < 16; ++b) { float d = vals[b] - mu; var += d * d; }
    var *= (1.f / 16.f);
    float sc = bng[o] * rsqrtf(var + 1e-5f);
    float sh = bnb[o] - mu * sc;
#pragma unroll
    for (int b = 0; b < 16; ++b)
      imge[b * 512 + o] = fmaxf(vals[b] * sc + sh, 0.f);
    return;
  }

  // two swizzled 64x512 fp8 h-buffers = 64 KB
  __shared__ __align__(16) unsigned char hbuf8[65536];

  const int b = blk >> 5, ipair = blk & 31;
  const int w = t >> 6, l = t & 63;
  const int quad = l >> 4, p16 = l & 15;

  // x rows for both tiles: lane l holds x[l*8 .. l*8+7]
  float xreg0[8], xreg1[8];
  {
    const float* xr0 = input + (size_t)(b * 64 + ipair * 2) * 512 + l * 8;
    *(float4*)xreg0       = *(const float4*)xr0;
    *(float4*)(xreg0 + 4) = *(const float4*)(xr0 + 4);
    *(float4*)xreg1       = *(const float4*)(xr0 + 512);
    *(float4*)(xreg1 + 4) = *(const float4*)(xr0 + 516);
  }

  f32x4 acc[4][8];

  // ---- phase 1: h1 = relu(A1' + W1br @ x), bf16 MFMA, both tiles -> fp8 LDS ----
  {
    bf16x8v xb[8];
#pragma unroll
    for (int mt = 0; mt < 4; ++mt) {
#pragma unroll
      for (int j = 0; j < 8; ++j) {
        float v0 = __shfl(xreg0[j], p16 + 16 * mt);
        float v1 = __shfl(xreg1[j], p16 + 16 * mt);
        xb[mt][j]     = (quad == 0) ? (__bf16)v0 : (__bf16)0.f;
        xb[mt + 4][j] = (quad == 0) ? (__bf16)v1 : (__bf16)0.f;
      }
    }
#pragma unroll
    for (int ot = 0; ot < 4; ++ot)
#pragma unroll
      for (int mt = 0; mt < 8; ++mt) { f32x4 z = {0.f, 0.f, 0.f, 0.f}; acc[ot][mt] = z; }
#pragma unroll
    for (int ot = 0; ot < 4; ++ot) {
      bf16x8v af = *(const bf16x8v*)(w1p + (w * 4 + ot) * 512 + l * 8);
#pragma unroll
      for (int mt = 0; mt < 8; ++mt)
        acc[ot][mt] = __builtin_amdgcn_mfma_f32_16x16x32_bf16(af, xb[mt], acc[ot][mt], 0, 0, 0);
    }
    const float4* cq = A1Q + ((size_t)b * 128 + w * 16) * 64;
#pragma unroll
    for (int ot = 0; ot < 4; ++ot) {
#pragma unroll
      for (int mtp = 0; mtp < 4; ++mtp) {
        float4 c = cq[(ot * 4 + quad) * 64 + 16 * mtp + p16];
        int row = p16 + 16 * mtp;
        int col = w * 64 + ot * 16 + quad * 4;
        int addr = row * 512 + (((col >> 3) ^ (row & 7)) << 3) + (col & 7);
#pragma unroll
        for (int tau = 0; tau < 2; ++tau) {
          f32x4 v = acc[ot][tau * 4 + mtp];
          unsigned pk = cvt4_fp8(fmaxf(v[0] + c.x, 0.f), fmaxf(v[1] + c.y, 0.f),
                                 fmaxf(v[2] + c.z, 0.f), fmaxf(v[3] + c.w, 0.f));
          *(unsigned*)(hbuf8 + tau * 32768 + addr) = pk;
        }
      }
    }
  }
  __syncthreads();

  // ---- phase 2: h2 = relu(h1 @ W2^T + b2), K=128 scaled fp8 ----
#pragma unroll
  for (int ot = 0; ot < 4; ++ot)
#pragma unroll
    for (int mt = 0; mt < 8; ++mt) { f32x4 z = {0.f, 0.f, 0.f, 0.f}; acc[ot][mt] = z; }

  kloop128(w2f8 + (size_t)(w * 4) * 8192 + l * 32, hbuf8, p16, quad, acc);
  __syncthreads();  // all h1 reads done before overwrite
#pragma unroll
  for (int ot = 0; ot < 4; ++ot) {
    float4 b2 = *(const float4*)(g2b + w * 64 + ot * 16 + quad * 4);
#pragma unroll
    for (int mt = 0; mt < 8; ++mt) {
      f32x4 v = acc[ot][mt];
      unsigned pk = cvt4_fp8(fmaxf(v[0] + b2.x, 0.f), fmaxf(v[1] + b2.y, 0.f),
                             fmaxf(v[2] + b2.z, 0.f), fmaxf(v[3] + b2.w, 0.f));
      int row = p16 + 16 * (mt & 3);
      int col = w * 64 + ot * 16 + quad * 4;
      *(unsigned*)(hbuf8 + (mt >> 2) * 32768 + row * 512 +
                   (((col >> 3) ^ (row & 7)) << 3) + (col & 7)) = pk;
    }
  }
  __syncthreads();

  // ---- phase 3: h3 = relu(h2 @ W3^T + b3), K=128 scaled fp8, fused mean ----
#pragma unroll
  for (int ot = 0; ot < 4; ++ot)
#pragma unroll
    for (int mt = 0; mt < 8; ++mt) { f32x4 z = {0.f, 0.f, 0.f, 0.f}; acc[ot][mt] = z; }

  kloop128(w3f8 + (size_t)(w * 4) * 8192 + l * 32, hbuf8, p16, quad, acc);

#pragma unroll
  for (int ot = 0; ot < 4; ++ot) {
    float4 b3 = *(const float4*)(g3b + w * 64 + ot * 16 + quad * 4);
    float bb[4] = {b3.x, b3.y, b3.z, b3.w};
#pragma unroll
    for (int r = 0; r < 4; ++r) {
      float s = 0.f;
#pragma unroll
      for (int mt = 0; mt < 8; ++mt) s += fmaxf(acc[ot][mt][r] + bb[r], 0.f);
      s += __shfl_xor(s, 1);
      s += __shfl_xor(s, 2);
      s += __shfl_xor(s, 4);
      s += __shfl_xor(s, 8);
      if (p16 == 0)
        atomicAdd(&sent[b * 512 + w * 64 + ot * 16 + quad * 4 + r], s * (1.0f / 4096.0f));
    }
  }
}

// ---------------------------------------------------------------------------
// Head: one block per b (512 thr, 8 waves). Wave v: rows v*64..v*64+63,
// wave-cooperative coalesced d1w reads, butterfly reduce, LDS cross-wave
// reduce, direct store.
// ---------------------------------------------------------------------------
__global__ __launch_bounds__(512) void k_head(
    const float* __restrict__ d1w, const float* __restrict__ d1b,
    const float* __restrict__ d2w, const float* __restrict__ d2b,
    const float* __restrict__ ws, float* __restrict__ out)
{
  __shared__ float emb[1024];
  __shared__ float red[8][2];
  const float* sent = (const float*)((const char*)ws + WS_SENT);
  const float* imge = (const float*)((const char*)ws + WS_IMGEMB);
  const int b = blockIdx.x, t = threadIdx.x;
  emb[t]       = sent[b * 512 + t];
  emb[512 + t] = imge[b * 512 + t];
  __syncthreads();
  const int v = t >> 6, l = t & 63;
  float p0 = 0.f, p1 = 0.f;
  for (int rr = 0; rr < 64; ++rr) {
    int row = v * 64 + rr;
    const float* wr = d1w + (size_t)row * 1024 + l * 4;
    float s = 0.f;
#pragma unroll
    for (int c = 0; c < 4; ++c) {
      float4 wv = *(const float4*)(wr + c * 256);
      float4 ev = *(const float4*)(emb + l * 4 + c * 256);
      s += wv.x * ev.x + wv.y * ev.y + wv.z * ev.z + wv.w * ev.w;
    }
#pragma unroll
    for (int m = 32; m >= 1; m >>= 1) s += __shfl_xor(s, m);
    float h = fmaxf(s + d1b[row], 0.f);
    p0 += d2w[row] * h;
    p1 += d2w[512 + row] * h;
  }
  if (l == 0) { red[v][0] = p0; red[v][1] = p1; }
  __syncthreads();
  if (t == 0) {
    float q0 = d2b[0], q1 = d2b[1];
#pragma unroll
    for (int u = 0; u < 8; ++u) { q0 += red[u][0]; q1 += red[u][1]; }
    out[b * 2 + 0] = q0;
    out[b * 2 + 1] = q1;
  }
}

// ---------------------------------------------------------------------------
extern "C" void kernel_launch(void* const* d_in, const int* in_sizes, int n_in,
                              void* d_out, int out_size, void* d_ws, size_t ws_size,
                              hipStream_t stream)
{
  const float* input    = (const float*)d_in[0];
  const float* im_input = (const float*)d_in[1];
  const float* g1w = (const float*)d_in[2];
  const float* g1b = (const float*)d_in[3];
  const float* g2w = (const float*)d_in[4];
  const float* g2b = (const float*)d_in[5];
  const float* g3w = (const float*)d_in[6];
  const float* g3b = (const float*)d_in[7];
  const float* imw = (const float*)d_in[8];
  const float* imb = (const float*)d_in[9];
  const float* bng = (const float*)d_in[10];
  const float* bnb = (const float*)d_in[11];
  const float* d1w = (const float*)d_in[12];
  const float* d1b = (const float*)d_in[13];
  const float* d2w = (const float*)d_in[14];
  const float* d2b = (const float*)d_in[15];
  float* out = (float*)d_out;
  float* ws  = (float*)d_ws;

  k_conv<<<848, 256, 0, stream>>>(input, im_input, g1w, g1b, g2w, g3w, imw, imb, ws);
  k_main<<<513, 512, 0, stream>>>(input, g2b, g3b, bng, bnb, ws);
  k_head<<<16, 512, 0, stream>>>(d1w, d1b, d2w, d2b, ws, out);
}

// Round 13
// 184.529 us; speedup vs baseline: 1.4443x; 1.4262x over previous
//
#include <hip/hip_runtime.h>

// ---------------------------------------------------------------------------
// Discriminator fused pipeline for MI355X (gfx950) — R10 configuration
// (measured best: 189 µs total, k_main 69.1 µs, absmax 2.0e-3).
//
// R11/R12 post-mortem (do not revisit): K=128 block-scaled MFMA cannot fit —
// acc[4][8]=128 AGPR + 8-VGPR A-frags x dbuf + 8-VGPR B-frags > 256-reg cap
// for 2 waves/SIMD; compiler spills to scratch (FETCH 214-222 MB, ~2x slower).
// R8 lesson: wave-per-tile split doubles weight L2 traffic (-11.6 µs).
//
//   h1[b, i*64+r, o] = relu( A1'[b*64+r, o] + sum_{t<8} W1br[o][t]*x_bi[r*8+t] )
//     A1' = input_flat @ W1a^T + b1  (k_conv tail: bf16 MFMA, C-frag out)
//   layers 2,3: transposed MFMA GEMMs D[o][m], fp8 e4m3 A (weights, L2) and
//   B (h, LDS). Two XOR-swizzled 32 KB fp8 h-buffers (64 KB LDS):
//     elem (tile T, r, c) at T*32768 + r*512 + (((c>>3) ^ (r&7))<<3) + (c&7)
//   Weight swizzle (fp8): elem (o,k) at
//     (o>>4)*8192 + (k>>5)*512 + (((k>>3)&3)*16 + (o&15))*8 + (k&7)
// ---------------------------------------------------------------------------

typedef float f32x4 __attribute__((ext_vector_type(4)));
typedef __bf16 bf16x8v __attribute__((ext_vector_type(8)));
typedef long i64;

__device__ __forceinline__ unsigned cvt4_fp8(float a, float b, float c, float d) {
  unsigned v = 0;
  v = __builtin_amdgcn_cvt_pk_fp8_f32(a, b, v, false);
  v = __builtin_amdgcn_cvt_pk_fp8_f32(c, d, v, true);
  return v;
}

// workspace byte offsets
#define WS_A1Q     0u           // 16 x 128 x 64 float4 = 2 MB  (A1+b1, C-frag layout)
#define WS_W1P     2097152u     // 512 x 32 bf16 = 32 KB (W1br zero-padded, A-swizzle)
#define WS_SENT    2129920u     // 16*512 f32 = 32 KB
#define WS_Y       2162688u     // 16*512 f32 = 32 KB (im-linear y)
#define WS_IMGEMB  2195456u     // 16*512 f32 = 32 KB
#define WS_W2F8    2228224u     // 512*512 fp8 = 256 KB (swizzled)
#define WS_W3F8    2490368u     // 512*512 fp8 = 256 KB (swizzled)
// total ~2.75 MB

// ---------------------------------------------------------------------------
// k_conv (848 blocks x 256 thr):
//   0..255    : W2 / W3 -> fp8 e4m3 swizzled
//   256..271  : W1br -> bf16 A-swizzle (K=32 pad) + sent zero
//   272..783  : im-linear y = im_input @ im_w^T + im_b
//   784..847  : A1' = input_flat @ W1a^T + b1 (bf16 MFMA, direct fp32 W1a reads)
// ---------------------------------------------------------------------------
__global__ __launch_bounds__(256) void k_conv(
    const float* __restrict__ input, const float* __restrict__ im_input,
    const float* __restrict__ g1w, const float* __restrict__ g1b,
    const float* __restrict__ g2w, const float* __restrict__ g3w,
    const float* __restrict__ imw, const float* __restrict__ imb,
    float* __restrict__ ws)
{
  __shared__ __align__(16) __bf16 xbuf[32768];   // 64x512 bf16, swizzled (A1 blocks)
  const int blk = blockIdx.x, t = threadIdx.x;
  __bf16* w1p  = (__bf16*)((char*)ws + WS_W1P);
  float* sent  = (float*)((char*)ws + WS_SENT);
  float* yv    = (float*)((char*)ws + WS_Y);
  unsigned char* w2f8 = (unsigned char*)ws + WS_W2F8;
  unsigned char* w3f8 = (unsigned char*)ws + WS_W3F8;
  float* A1Qf = ws;

  if (blk < 256) {
    // W2 / W3 -> fp8 swizzled
    int idx = (blk * 256 + t) * 8;            // 0..524288-8
    const float* src; unsigned char* dst; int off;
    if (idx < 262144) { src = g2w; dst = w2f8; off = idx; }
    else              { src = g3w; dst = w3f8; off = idx - 262144; }
    int o = off >> 9, k = off & 511;
    int ks = k >> 5, quad = (k >> 3) & 3;
    int doff = (o >> 4) * 8192 + ks * 512 + (quad * 16 + (o & 15)) * 8;
    float4 v0 = *(const float4*)(src + off);
    float4 v1 = *(const float4*)(src + off + 4);
    uint2 pk;
    pk.x = cvt4_fp8(v0.x, v0.y, v0.z, v0.w);
    pk.y = cvt4_fp8(v1.x, v1.y, v1.z, v1.w);
    *(uint2*)(dst + doff) = pk;
  } else if (blk < 272) {
    // W1P[o][s] = sum_{u<64} gmlp1_w[o][512 + s*64 + u], bf16, A-swizzle, K=32 pad
    int idx = (blk - 256) * 256 + t;      // 0..4095
    int o = idx >> 3, s = idx & 7;
    const float* p = g1w + (size_t)o * 1024 + 512 + s * 64;
    float sum = 0.f;
#pragma unroll
    for (int u = 0; u < 64; u += 4) {
      float4 v = *(const float4*)(p + u);
      sum += v.x + v.y + v.z + v.w;
    }
    int base = (o >> 4) * 512 + (o & 15) * 8 + s;   // quad 0 slot
    w1p[base]       = (__bf16)sum;
    w1p[base + 128] = (__bf16)0.f;                  // quads 1..3 = zero pad
    w1p[base + 256] = (__bf16)0.f;
    w1p[base + 384] = (__bf16)0.f;
    sent[idx] = 0.f; sent[idx + 4096] = 0.f;        // zero accumulator
  } else if (blk < 784) {
    // y[b][o] = dot(im_input[b], im_w[o]) + im_b[o]; one block per o
    int o = blk - 272;                    // 0..511
    int wv = t >> 6, l = t & 63;
    const float* wrow = imw + (size_t)o * 2048;
    for (int bb = 0; bb < 4; ++bb) {
      int b = wv * 4 + bb;
      const float* xr = im_input + (size_t)b * 2048;
      float s = 0.f;
#pragma unroll
      for (int u = 0; u < 8; ++u) {
        int k = u * 256 + l * 4;
        float4 xv = *(const float4*)(xr + k);
        float4 wx = *(const float4*)(wrow + k);
        s += xv.x * wx.x + xv.y * wx.y + xv.z * wx.z + xv.w * wx.w;
      }
#pragma unroll
      for (int m = 32; m >= 1; m >>= 1) s += __shfl_xor(s, m);
      if (l == 0) yv[b * 512 + o] = s + imb[o];
    }
  } else {
    // A1' GEMM: 64 blocks = (b, o-quarter q). Wave w: o-span q*128 + w*32.
    int pb = blk - 784;
    int b = pb >> 2, q = pb & 3;
#pragma unroll
    for (int it = 0; it < 16; ++it) {
      int id = t + 256 * it;
      int r = id >> 6, oc = id & 63;
      const float* src = input + (size_t)(b * 64 + r) * 512 + oc * 8;
      float4 v0 = *(const float4*)src;
      float4 v1 = *(const float4*)(src + 4);
      bf16x8v h;
      h[0] = (__bf16)v0.x; h[1] = (__bf16)v0.y; h[2] = (__bf16)v0.z; h[3] = (__bf16)v0.w;
      h[4] = (__bf16)v1.x; h[5] = (__bf16)v1.y; h[6] = (__bf16)v1.z; h[7] = (__bf16)v1.w;
      *(bf16x8v*)(xbuf + r * 512 + ((oc ^ (r & 7)) << 3)) = h;
    }
    __syncthreads();
    const int w = t >> 6, l = t & 63;
    const int quad = l >> 4, p16 = l & 15;
    const int msk3 = (p16 & 7) << 3;
    f32x4 acc2[2][4];
#pragma unroll
    for (int ot = 0; ot < 2; ++ot)
#pragma unroll
      for (int mt = 0; mt < 4; ++mt) { f32x4 z = {0.f, 0.f, 0.f, 0.f}; acc2[ot][mt] = z; }
    const float* wbase = g1w + (size_t)(q * 128 + w * 32 + p16) * 1024;
#pragma unroll 2
    for (int ks = 0; ks < 16; ++ks) {
      const int kcb = (((ks * 4 + quad) << 3) ^ msk3);
      bf16x8v bf[4];
#pragma unroll
      for (int mt = 0; mt < 4; ++mt)
        bf[mt] = *(const bf16x8v*)(xbuf + (p16 + 16 * mt) * 512 + kcb);
#pragma unroll
      for (int ot = 0; ot < 2; ++ot) {
        const float* ap = wbase + ot * 16384 + ks * 32 + quad * 8;
        float4 f0 = *(const float4*)ap;
        float4 f1 = *(const float4*)(ap + 4);
        bf16x8v af;
        af[0] = (__bf16)f0.x; af[1] = (__bf16)f0.y; af[2] = (__bf16)f0.z; af[3] = (__bf16)f0.w;
        af[4] = (__bf16)f1.x; af[5] = (__bf16)f1.y; af[6] = (__bf16)f1.z; af[7] = (__bf16)f1.w;
#pragma unroll
        for (int mt = 0; mt < 4; ++mt)
          acc2[ot][mt] = __builtin_amdgcn_mfma_f32_16x16x32_bf16(af, bf[mt], acc2[ot][mt], 0, 0, 0);
      }
    }
#pragma unroll
    for (int ot = 0; ot < 2; ++ot) {
      int o = q * 128 + w * 32 + ot * 16 + quad * 4;
      float4 bias = *(const float4*)(g1b + o);
      float bb[4] = {bias.x, bias.y, bias.z, bias.w};
      size_t o4 = (size_t)b * 128 + (o >> 2);
#pragma unroll
      for (int mt = 0; mt < 4; ++mt)
#pragma unroll
        for (int r = 0; r < 4; ++r)
          A1Qf[(o4 * 64 + mt * 16 + p16) * 4 + r] = acc2[ot][mt][r] + bb[r];
    }
  }
}

// ---------------------------------------------------------------------------
// FP8 transposed-GEMM K-loop, two-tile (M=128): 4 A-frags x 8 B-frags per ks.
// R4 prefetch schedule (measured best). All addresses in BYTES.
// ---------------------------------------------------------------------------
__device__ __forceinline__ void kloop8(const unsigned char* __restrict__ wl,
                                       const unsigned char* __restrict__ hbuf,
                                       int p16, int quad, f32x4 acc[4][8])
{
  const int msk3 = (p16 & 7) << 3;
  int moff[8];
#pragma unroll
  for (int mt = 0; mt < 8; ++mt)
    moff[mt] = (mt >> 2) * 32768 + (p16 + 16 * (mt & 3)) * 512;
  i64 a[4], an[4];
#pragma unroll
  for (int ot = 0; ot < 4; ++ot) a[ot] = *(const i64*)(wl + ot * 8192);
#pragma unroll 2
  for (int ks = 0; ks < 16; ++ks) {
    const int kcb = (((ks * 4 + quad) << 3) ^ msk3);
    i64 bf[8];
#pragma unroll
    for (int mt = 0; mt < 8; ++mt)
      bf[mt] = *(const i64*)(hbuf + moff[mt] + kcb);
    if (ks < 15) {
#pragma unroll
      for (int ot = 0; ot < 4; ++ot)
        an[ot] = *(const i64*)(wl + (ks + 1) * 512 + ot * 8192);
    }
#pragma unroll
    for (int ot = 0; ot < 4; ++ot)
#pragma unroll
      for (int mt = 0; mt < 4; ++mt)
        acc[ot][mt] = __builtin_amdgcn_mfma_f32_16x16x32_fp8_fp8(a[ot], bf[mt], acc[ot][mt], 0, 0, 0);
#pragma unroll
    for (int ot = 0; ot < 4; ++ot)
#pragma unroll
      for (int mt = 4; mt < 8; ++mt)
        acc[ot][mt] = __builtin_amdgcn_mfma_f32_16x16x32_fp8_fp8(a[ot], bf[mt], acc[ot][mt], 0, 0, 0);
    if (ks < 15) {
#pragma unroll
      for (int ot = 0; ot < 4; ++ot) a[ot] = an[ot];
    }
  }
}

// ---------------------------------------------------------------------------
// Main fused kernel: blocks 0..511 = (b, i-pair) tiles (512 thr, 8 waves,
// two 32 KB fp8 LDS h-buffers); block 512 = BatchNorm.
// Wave w covers o in [w*64, w*64+64) via 4 ot; mt 0..3 = tile0, 4..7 = tile1.
// ---------------------------------------------------------------------------
__global__ __launch_bounds__(512, 2) void k_main(
    const float* __restrict__ input,
    const float* __restrict__ g2b, const float* __restrict__ g3b,
    const float* __restrict__ bng, const float* __restrict__ bnb,
    float* __restrict__ ws)
{
  const int blk = blockIdx.x, t = threadIdx.x;
  const float4* A1Q = (const float4*)ws;
  const __bf16* w1p = (const __bf16*)((char*)ws + WS_W1P);
  float* sent = (float*)((char*)ws + WS_SENT);
  float* yv   = (float*)((char*)ws + WS_Y);
  float* imge = (float*)((char*)ws + WS_IMGEMB);
  const unsigned char* w2f8 = (const unsigned char*)ws + WS_W2F8;
  const unsigned char* w3f8 = (const unsigned char*)ws + WS_W3F8;

  if (blk == 512) {
    // BatchNorm1d (training-mode batch stats) + ReLU over y[16][512]
    int o = t;
    float vals[16];
    float mu = 0.f;
#pragma unroll
    for (int b = 0; b < 16; ++b) { vals[b] = yv[b * 512 + o]; mu += vals[b]; }
    mu *= (1.f / 16.f);
    float var = 0.f;
#pragma unroll
    for (int b = 0; b < 16; ++b) { float d = vals[b] - mu; var += d * d; }
    var *= (1.f / 16.f);
    float sc = bng[o] * rsqrtf(var + 1e-5f);
    float sh = bnb[o] - mu * sc;
#pragma unroll
    for (int b = 0; b < 16; ++b)
      imge[b * 512 + o] = fmaxf(vals[b] * sc + sh, 0.f);
    return;
  }

  // two swizzled 64x512 fp8 h-buffers = 64 KB
  __shared__ __align__(16) unsigned char hbuf8[65536];

  const int b = blk >> 5, ipair = blk & 31;
  const int w = t >> 6, l = t & 63;
  const int quad = l >> 4, p16 = l & 15;

  // x rows for both tiles: lane l holds x[l*8 .. l*8+7]
  float xreg0[8], xreg1[8];
  {
    const float* xr0 = input + (size_t)(b * 64 + ipair * 2) * 512 + l * 8;
    *(float4*)xreg0       = *(const float4*)xr0;
    *(float4*)(xreg0 + 4) = *(const float4*)(xr0 + 4);
    *(float4*)xreg1       = *(const float4*)(xr0 + 512);
    *(float4*)(xreg1 + 4) = *(const float4*)(xr0 + 516);
  }

  f32x4 acc[4][8];

  // ---- phase 1: h1 = relu(A1' + W1br @ x), bf16 MFMA, both tiles -> fp8 LDS ----
  {
    bf16x8v xb[8];
#pragma unroll
    for (int mt = 0; mt < 4; ++mt) {
#pragma unroll
      for (int j = 0; j < 8; ++j) {
        float v0 = __shfl(xreg0[j], p16 + 16 * mt);
        float v1 = __shfl(xreg1[j], p16 + 16 * mt);
        xb[mt][j]     = (quad == 0) ? (__bf16)v0 : (__bf16)0.f;
        xb[mt + 4][j] = (quad == 0) ? (__bf16)v1 : (__bf16)0.f;
      }
    }
#pragma unroll
    for (int ot = 0; ot < 4; ++ot)
#pragma unroll
      for (int mt = 0; mt < 8; ++mt) { f32x4 z = {0.f, 0.f, 0.f, 0.f}; acc[ot][mt] = z; }
#pragma unroll
    for (int ot = 0; ot < 4; ++ot) {
      bf16x8v af = *(const bf16x8v*)(w1p + (w * 4 + ot) * 512 + l * 8);
#pragma unroll
      for (int mt = 0; mt < 8; ++mt)
        acc[ot][mt] = __builtin_amdgcn_mfma_f32_16x16x32_bf16(af, xb[mt], acc[ot][mt], 0, 0, 0);
    }
    const float4* cq = A1Q + ((size_t)b * 128 + w * 16) * 64;
#pragma unroll
    for (int ot = 0; ot < 4; ++ot) {
#pragma unroll
      for (int mtp = 0; mtp < 4; ++mtp) {
        float4 c = cq[(ot * 4 + quad) * 64 + 16 * mtp + p16];
        int row = p16 + 16 * mtp;
        int col = w * 64 + ot * 16 + quad * 4;
        int addr = row * 512 + (((col >> 3) ^ (row & 7)) << 3) + (col & 7);
#pragma unroll
        for (int tau = 0; tau < 2; ++tau) {
          f32x4 v = acc[ot][tau * 4 + mtp];
          unsigned pk = cvt4_fp8(fmaxf(v[0] + c.x, 0.f), fmaxf(v[1] + c.y, 0.f),
                                 fmaxf(v[2] + c.z, 0.f), fmaxf(v[3] + c.w, 0.f));
          *(unsigned*)(hbuf8 + tau * 32768 + addr) = pk;
        }
      }
    }
  }
  __syncthreads();

  // ---- phase 2: h2 = relu(h1 @ W2^T + b2), fp8 ----
#pragma unroll
  for (int ot = 0; ot < 4; ++ot)
#pragma unroll
    for (int mt = 0; mt < 8; ++mt) { f32x4 z = {0.f, 0.f, 0.f, 0.f}; acc[ot][mt] = z; }

  kloop8(w2f8 + (size_t)(w * 4) * 8192 + l * 8, hbuf8, p16, quad, acc);
  __syncthreads();  // all h1 reads done before overwrite
#pragma unroll
  for (int ot = 0; ot < 4; ++ot) {
    float4 b2 = *(const float4*)(g2b + w * 64 + ot * 16 + quad * 4);
#pragma unroll
    for (int mt = 0; mt < 8; ++mt) {
      f32x4 v = acc[ot][mt];
      unsigned pk = cvt4_fp8(fmaxf(v[0] + b2.x, 0.f), fmaxf(v[1] + b2.y, 0.f),
                             fmaxf(v[2] + b2.z, 0.f), fmaxf(v[3] + b2.w, 0.f));
      int row = p16 + 16 * (mt & 3);
      int col = w * 64 + ot * 16 + quad * 4;
      *(unsigned*)(hbuf8 + (mt >> 2) * 32768 + row * 512 +
                   (((col >> 3) ^ (row & 7)) << 3) + (col & 7)) = pk;
    }
  }
  __syncthreads();

  // ---- phase 3: h3 = relu(h2 @ W3^T + b3), fp8, fused mean-reduce ----
#pragma unroll
  for (int ot = 0; ot < 4; ++ot)
#pragma unroll
    for (int mt = 0; mt < 8; ++mt) { f32x4 z = {0.f, 0.f, 0.f, 0.f}; acc[ot][mt] = z; }

  kloop8(w3f8 + (size_t)(w * 4) * 8192 + l * 8, hbuf8, p16, quad, acc);

#pragma unroll
  for (int ot = 0; ot < 4; ++ot) {
    float4 b3 = *(const float4*)(g3b + w * 64 + ot * 16 + quad * 4);
    float bb[4] = {b3.x, b3.y, b3.z, b3.w};
#pragma unroll
    for (int r = 0; r < 4; ++r) {
      float s = 0.f;
#pragma unroll
      for (int mt = 0; mt < 8; ++mt) s += fmaxf(acc[ot][mt][r] + bb[r], 0.f);
      s += __shfl_xor(s, 1);
      s += __shfl_xor(s, 2);
      s += __shfl_xor(s, 4);
      s += __shfl_xor(s, 8);
      if (p16 == 0)
        atomicAdd(&sent[b * 512 + w * 64 + ot * 16 + quad * 4 + r], s * (1.0f / 4096.0f));
    }
  }
}

// ---------------------------------------------------------------------------
// Head: one block per b (512 thr, 8 waves). Wave v: rows v*64..v*64+63,
// wave-cooperative coalesced d1w reads, butterfly reduce, LDS cross-wave
// reduce, direct store.
// ---------------------------------------------------------------------------
__global__ __launch_bounds__(512) void k_head(
    const float* __restrict__ d1w, const float* __restrict__ d1b,
    const float* __restrict__ d2w, const float* __restrict__ d2b,
    const float* __restrict__ ws, float* __restrict__ out)
{
  __shared__ float emb[1024];
  __shared__ float red[8][2];
  const float* sent = (const float*)((const char*)ws + WS_SENT);
  const float* imge = (const float*)((const char*)ws + WS_IMGEMB);
  const int b = blockIdx.x, t = threadIdx.x;
  emb[t]       = sent[b * 512 + t];
  emb[512 + t] = imge[b * 512 + t];
  __syncthreads();
  const int v = t >> 6, l = t & 63;
  float p0 = 0.f, p1 = 0.f;
  for (int rr = 0; rr < 64; ++rr) {
    int row = v * 64 + rr;
    const float* wr = d1w + (size_t)row * 1024 + l * 4;
    float s = 0.f;
#pragma unroll
    for (int c = 0; c < 4; ++c) {
      float4 wv = *(const float4*)(wr + c * 256);
      float4 ev = *(const float4*)(emb + l * 4 + c * 256);
      s += wv.x * ev.x + wv.y * ev.y + wv.z * ev.z + wv.w * ev.w;
    }
#pragma unroll
    for (int m = 32; m >= 1; m >>= 1) s += __shfl_xor(s, m);
    float h = fmaxf(s + d1b[row], 0.f);
    p0 += d2w[row] * h;
    p1 += d2w[512 + row] * h;
  }
  if (l == 0) { red[v][0] = p0; red[v][1] = p1; }
  __syncthreads();
  if (t == 0) {
    float q0 = d2b[0], q1 = d2b[1];
#pragma unroll
    for (int u = 0; u < 8; ++u) { q0 += red[u][0]; q1 += red[u][1]; }
    out[b * 2 + 0] = q0;
    out[b * 2 + 1] = q1;
  }
}

// ---------------------------------------------------------------------------
extern "C" void kernel_launch(void* const* d_in, const int* in_sizes, int n_in,
                              void* d_out, int out_size, void* d_ws, size_t ws_size,
                              hipStream_t stream)
{
  const float* input    = (const float*)d_in[0];
  const float* im_input = (const float*)d_in[1];
  const float* g1w = (const float*)d_in[2];
  const float* g1b = (const float*)d_in[3];
  const float* g2w = (const float*)d_in[4];
  const float* g2b = (const float*)d_in[5];
  const float* g3w = (const float*)d_in[6];
  const float* g3b = (const float*)d_in[7];
  const float* imw = (const float*)d_in[8];
  const float* imb = (const float*)d_in[9];
  const float* bng = (const float*)d_in[10];
  const float* bnb = (const float*)d_in[11];
  const float* d1w = (const float*)d_in[12];
  const float* d1b = (const float*)d_in[13];
  const float* d2w = (const float*)d_in[14];
  const float* d2b = (const float*)d_in[15];
  float* out = (float*)d_out;
  float* ws  = (float*)d_ws;

  k_conv<<<848, 256, 0, stream>>>(input, im_input, g1w, g1b, g2w, g3w, imw, imb, ws);
  k_main<<<513, 512, 0, stream>>>(input, g2b, g3b, bng, bnb, ws);
  k_head<<<16, 512, 0, stream>>>(d1w, d1b, d2w, d2b, ws, out);
}